// Round 17
// baseline (1182.494 us; speedup 1.0000x reference)
//
#include <hip/hip_runtime.h>

#define NN 100000
#define NE 1600000
#define FI 128
#define FH 64
#define FO 40
#define NR 500      // dst ranges
#define RSZ 200     // nodes per range (NR*RSZ == NN)
#define NBK 512     // histogram/scatter blocks

typedef _Float16 f16;

// ---------------- Threefry-2x32, key = (0, 42) -----------------------------
__device__ __forceinline__ unsigned rotl32(unsigned v, unsigned r) {
    return (v << r) | (v >> (32u - r));
}

__device__ __forceinline__ void threefry_0_42(unsigned x0, unsigned x1,
                                              unsigned& o0, unsigned& o1) {
    const unsigned k0 = 0u, k1 = 42u;
    const unsigned k2 = 0x1BD11BDAu ^ k0 ^ k1;
    x0 += k0; x1 += k1;
#define TFR(r) { x0 += x1; x1 = rotl32(x1, r); x1 ^= x0; }
    TFR(13) TFR(15) TFR(26) TFR(6)   x0 += k1; x1 += k2 + 1u;
    TFR(17) TFR(29) TFR(16) TFR(24)  x0 += k2; x1 += k0 + 2u;
    TFR(13) TFR(15) TFR(26) TFR(6)   x0 += k0; x1 += k1 + 3u;
    TFR(17) TFR(29) TFR(16) TFR(24)  x0 += k1; x1 += k2 + 4u;
    TFR(13) TFR(15) TFR(26) TFR(6)   x0 += k2; x1 += k0 + 5u;
#undef TFR
    o0 = x0; o1 = x1;
}

__device__ __forceinline__ void unpack2(unsigned u, float& lo, float& hi) {
    union { unsigned u; f16 h[2]; } c;
    c.u = u;
    lo = (float)c.h[0];
    hi = (float)c.h[1];
}

// select one of 4 wave-uniform values by per-lane parity p (0..3)
__device__ __forceinline__ int sel4(int p, int s0, int s1, int s2, int s3) {
    int t0 = (p & 1) ? s1 : s0;
    int t1 = (p & 1) ? s3 : s2;
    return (p & 2) ? t1 : t0;
}

// ---------------- P1: per-block LDS range histogram ------------------------
__global__ __launch_bounds__(256) void k_p1(const int* __restrict__ ei,
                                            int* __restrict__ blkhist) {
    __shared__ int h[NR];
    int t = threadIdx.x, b = blockIdx.x;
    for (int i = t; i < NR; i += 256) h[i] = 0;
    __syncthreads();
    for (int i = b * 256 + t; i < NE; i += NBK * 256) {
        int d = ei[NE + i];
        atomicAdd(&h[d / RSZ], 1);               // LDS atomic
    }
    __syncthreads();
    for (int i = t; i < NR; i += 256) blkhist[(size_t)b * NR + i] = h[i];
}

// ---------------- scanR1: per-range exclusive scan over blocks -------------
__global__ __launch_bounds__(512) void k_scanR1(int* __restrict__ blkhist,
                                                int* __restrict__ rtot) {
    __shared__ int sh[NBK];
    int r = blockIdx.x, t = threadIdx.x;
    int v = blkhist[(size_t)t * NR + r];
    sh[t] = v;
    __syncthreads();
    for (int off = 1; off < NBK; off <<= 1) {
        int u = (t >= off) ? sh[t - off] : 0;
        __syncthreads();
        sh[t] += u;
        __syncthreads();
    }
    blkhist[(size_t)t * NR + r] = sh[t] - v;     // block-local prefix
    if (t == NBK - 1) rtot[r] = sh[t];
}

// ---------------- scanR2: exclusive scan of range totals -------------------
__global__ __launch_bounds__(512) void k_scanR2(const int* __restrict__ rtot,
                                                int* __restrict__ rangeBase) {
    __shared__ int sh[512];
    int t = threadIdx.x;
    int v = (t < NR) ? rtot[t] : 0;
    sh[t] = v;
    __syncthreads();
    for (int off = 1; off < 512; off <<= 1) {
        int u = (t >= off) ? sh[t - off] : 0;
        __syncthreads();
        sh[t] += u;
        __syncthreads();
    }
    if (t < NR) rangeBase[t] = sh[t] - v;
    if (t == NR - 1) rangeBase[NR] = sh[t];      // == NE
}

// ---------------- P2: scatter edges into range buckets (LDS cursors) -------
__global__ __launch_bounds__(256) void k_p2(const int* __restrict__ ei,
                                            const int* __restrict__ blkhist,
                                            const int* __restrict__ rangeBase,
                                            int2* __restrict__ bucket) {
    __shared__ int cur[NR];
    int t = threadIdx.x, b = blockIdx.x;
    for (int i = t; i < NR; i += 256)
        cur[i] = rangeBase[i] + blkhist[(size_t)b * NR + i];
    __syncthreads();
    for (int i = b * 256 + t; i < NE; i += NBK * 256) {   // same slice as k_p1
        int s = ei[i];
        int d = ei[NE + i];
        int pos = atomicAdd(&cur[d / RSZ], 1);            // LDS atomic
        bucket[pos] = make_int2(s, d);
    }
}

// ---------------- k_cnt: per-node degree -> inv ----------------------------
__global__ __launch_bounds__(256) void k_cnt(const int2* __restrict__ bucket,
                                             const int* __restrict__ rangeBase,
                                             float* __restrict__ inv) {
    __shared__ int cnt[RSZ];
    int t = threadIdx.x, r = blockIdx.x;
    int e0 = rangeBase[r], e1 = rangeBase[r + 1];
    int n0 = r * RSZ;
    if (t < RSZ) cnt[t] = 0;
    __syncthreads();
    for (int i = e0 + t; i < e1; i += 256)
        atomicAdd(&cnt[bucket[i].y - n0], 1);             // LDS atomic
    __syncthreads();
    if (t < RSZ) inv[n0 + t] = rsqrtf((float)cnt[t] + 1.0f);
}

// ---------------- GEMM1: h0s[N,64] = (x @ W1) * inv[row] (fp16, +zero row) -
#define XS_STRIDE 132   // 128 + 4: keeps b128 16B-aligned; rows on distinct banks
__global__ __launch_bounds__(256) void k_gemm1(const float* __restrict__ x,
                                               const float* __restrict__ W1,
                                               const float* __restrict__ inv,
                                               f16* __restrict__ h0s) {
    __shared__ float xs[64 * XS_STRIDE];   // 33.8 KB
    __shared__ float ws[64 * FH];          // 16 KB (one K-half of W1)
    int t = threadIdx.x;
    int row0 = blockIdx.x * 64;
    {
        int r = t >> 5;              // 0..7
        int c4 = (t & 31) * 4;       // 0..124
#pragma unroll
        for (int p = 0; p < 8; ++p) {
            int row = row0 + r + p * 8;
            float4 v = make_float4(0.f, 0.f, 0.f, 0.f);
            if (row < NN) v = *(const float4*)&x[(size_t)row * FI + c4];
            *(float4*)&xs[(r + p * 8) * XS_STRIDE + c4] = v;
        }
    }
    float acc[4][4] = {{0.f}};
    int tx4 = (t & 15) * 4;
    int ty4 = (t >> 4) * 4;
#pragma unroll
    for (int half = 0; half < 2; ++half) {
        __syncthreads();
        {
            const float4* Wv = (const float4*)(W1 + half * 64 * FH);
            float4* wv = (float4*)ws;
            for (int i = t; i < 64 * FH / 4; i += 256) wv[i] = Wv[i];
        }
        __syncthreads();
#pragma unroll 2
        for (int k = 0; k < 64; k += 4) {
            float4 a0 = *(const float4*)&xs[(ty4 + 0) * XS_STRIDE + half * 64 + k];
            float4 a1 = *(const float4*)&xs[(ty4 + 1) * XS_STRIDE + half * 64 + k];
            float4 a2 = *(const float4*)&xs[(ty4 + 2) * XS_STRIDE + half * 64 + k];
            float4 a3 = *(const float4*)&xs[(ty4 + 3) * XS_STRIDE + half * 64 + k];
            float4 b0 = *(const float4*)&ws[(k + 0) * FH + tx4];
            float4 b1 = *(const float4*)&ws[(k + 1) * FH + tx4];
            float4 b2 = *(const float4*)&ws[(k + 2) * FH + tx4];
            float4 b3 = *(const float4*)&ws[(k + 3) * FH + tx4];
#define KK1(AE, BV) \
            acc[0][0] = fmaf(a0.AE, BV.x, acc[0][0]); \
            acc[0][1] = fmaf(a0.AE, BV.y, acc[0][1]); \
            acc[0][2] = fmaf(a0.AE, BV.z, acc[0][2]); \
            acc[0][3] = fmaf(a0.AE, BV.w, acc[0][3]); \
            acc[1][0] = fmaf(a1.AE, BV.x, acc[1][0]); \
            acc[1][1] = fmaf(a1.AE, BV.y, acc[1][1]); \
            acc[1][2] = fmaf(a1.AE, BV.z, acc[1][2]); \
            acc[1][3] = fmaf(a1.AE, BV.w, acc[1][3]); \
            acc[2][0] = fmaf(a2.AE, BV.x, acc[2][0]); \
            acc[2][1] = fmaf(a2.AE, BV.y, acc[2][1]); \
            acc[2][2] = fmaf(a2.AE, BV.z, acc[2][2]); \
            acc[2][3] = fmaf(a2.AE, BV.w, acc[2][3]); \
            acc[3][0] = fmaf(a3.AE, BV.x, acc[3][0]); \
            acc[3][1] = fmaf(a3.AE, BV.y, acc[3][1]); \
            acc[3][2] = fmaf(a3.AE, BV.z, acc[3][2]); \
            acc[3][3] = fmaf(a3.AE, BV.w, acc[3][3]);
            KK1(x, b0) KK1(y, b1) KK1(z, b2) KK1(w, b3)
#undef KK1
        }
    }
#pragma unroll
    for (int i = 0; i < 4; ++i) {
        int row = row0 + ty4 + i;
        if (row < NN) {
            float s = inv[row];
            union { f16 h[4]; uint2 u; } p;
            p.h[0] = (f16)(acc[i][0] * s);
            p.h[1] = (f16)(acc[i][1] * s);
            p.h[2] = (f16)(acc[i][2] * s);
            p.h[3] = (f16)(acc[i][3] * s);
            *(uint2*)&h0s[(size_t)row * FH + tx4] = p.u;
        } else if (row == NN) {
            *(uint2*)&h0s[(size_t)row * FH + tx4] = make_uint2(0u, 0u);  // guard row
        }
    }
}

// ---------------- agg1: block-per-range LDS accumulate ---------------------
// acc[200][64] f32 in LDS (51.2 KB), init = self terms; stream edges with
// quad-parity gathers + ds_add_f32; dense epilogue (bias/relu/dropout).
__global__ __launch_bounds__(256) void k_agg1(const int2* __restrict__ bucket,
                                              const int* __restrict__ rangeBase,
                                              const float* __restrict__ inv,
                                              const f16* __restrict__ h0s,
                                              const float* __restrict__ b1,
                                              f16* __restrict__ h1s) {
    __shared__ float acc[RSZ * FH];            // 51.2 KB
    int t = threadIdx.x, r = blockIdx.x;
    int n0 = r * RSZ;
    int e0 = __builtin_amdgcn_readfirstlane(rangeBase[r]);
    int e1 = __builtin_amdgcn_readfirstlane(rangeBase[r + 1]);
    // init with self terms (coalesced f16 reads, contiguous LDS writes)
    for (int idx = t; idx < RSZ * FH; idx += 256)
        acc[idx] = (float)h0s[(size_t)n0 * FH + idx];
    __syncthreads();
    int lane = t & 63;
    int wid = t >> 6;                          // 0..3
    int p = lane >> 4;                         // edge parity 0..3
    int c4 = (lane & 15) * 4;
    size_t q8 = (size_t)(lane & 15) * 8;
    const char* hb = (const char*)h0s;
    for (int i = e0 + wid * 4; i < e1; i += 16) {
        int2 ed0 = bucket[i + 0];
        int2 ed1 = bucket[i + 1];
        int2 ed2 = bucket[i + 2];
        int2 ed3 = bucket[i + 3];
        int s_p = sel4(p, ed0.x, ed1.x, ed2.x, ed3.x);
        int d_p = sel4(p, ed0.y, ed1.y, ed2.y, ed3.y);
        if (i + p >= e1) { s_p = NN; d_p = n0; }     // gather zero row, add to node n0
        uint2 u = *(const uint2*)(hb + ((size_t)s_p << 7) + q8);
        float f0, f1, f2, f3;
        unpack2(u.x, f0, f1);
        unpack2(u.y, f2, f3);
        int base = (d_p - n0) * FH + c4;
        atomicAdd(&acc[base + 0], f0);
        atomicAdd(&acc[base + 1], f1);
        atomicAdd(&acc[base + 2], f2);
        atomicAdd(&acc[base + 3], f3);
    }
    __syncthreads();
    // epilogue: scale + bias + relu + dropout -> h1s (contiguous stores)
    for (int idx = t; idx < RSZ * FH; idx += 256) {
        int dloc = idx >> 6, f = idx & 63;
        int d = n0 + dloc;
        float v = fmaxf(acc[idx] * inv[d] + b1[f], 0.f);
        unsigned o0, o1;
        threefry_0_42(0u, (unsigned)(d * FH + f), o0, o1);
        h1s[(size_t)n0 * FH + idx] = (f16)((((o0 ^ o1) >> 31)) ? 0.f : v * 2.f);
    }
}

// ---------------- GEMM2: h2s[N,64pad] = (h1s @ W2) * inv[row] (f16 in/out) -
#define HS_STRIDE 68    // 64 + 4: b128-aligned, rows on distinct banks
__global__ __launch_bounds__(256) void k_gemm2(const f16* __restrict__ h1s,
                                               const float* __restrict__ W2,
                                               const float* __restrict__ inv,
                                               f16* __restrict__ h2s) {
    __shared__ float hs[64 * HS_STRIDE];   // 17.4 KB
    __shared__ float ws[FH * 64];          // 16 KB, cols 40..63 zero
    int t = threadIdx.x;
    int row0 = blockIdx.x * 64;
    {
        int r = t >> 4;              // 0..15
        int c4 = (t & 15) * 4;       // 0..60
#pragma unroll
        for (int p = 0; p < 4; ++p) {
            int row = row0 + r + p * 16;
            float4 v = make_float4(0.f, 0.f, 0.f, 0.f);
            if (row < NN) {
                uint2 u = *(const uint2*)&h1s[(size_t)row * FH + c4];
                unpack2(u.x, v.x, v.y);
                unpack2(u.y, v.z, v.w);
            }
            *(float4*)&hs[(r + p * 16) * HS_STRIDE + c4] = v;
        }
    }
    for (int i = t; i < FH * 64; i += 256) {
        int r = i >> 6, c = i & 63;
        ws[i] = (c < FO) ? W2[r * FO + c] : 0.f;
    }
    __syncthreads();
    float acc[4][4] = {{0.f}};
    int tx4 = (t & 15) * 4;
    int ty4 = (t >> 4) * 4;
#pragma unroll 2
    for (int k = 0; k < FH; k += 4) {
        float4 a0 = *(const float4*)&hs[(ty4 + 0) * HS_STRIDE + k];
        float4 a1 = *(const float4*)&hs[(ty4 + 1) * HS_STRIDE + k];
        float4 a2 = *(const float4*)&hs[(ty4 + 2) * HS_STRIDE + k];
        float4 a3 = *(const float4*)&hs[(ty4 + 3) * HS_STRIDE + k];
        float4 b0 = *(const float4*)&ws[(k + 0) * 64 + tx4];
        float4 b1 = *(const float4*)&ws[(k + 1) * 64 + tx4];
        float4 b2 = *(const float4*)&ws[(k + 2) * 64 + tx4];
        float4 b3 = *(const float4*)&ws[(k + 3) * 64 + tx4];
#define KK2(AE, BV) \
        acc[0][0] = fmaf(a0.AE, BV.x, acc[0][0]); \
        acc[0][1] = fmaf(a0.AE, BV.y, acc[0][1]); \
        acc[0][2] = fmaf(a0.AE, BV.z, acc[0][2]); \
        acc[0][3] = fmaf(a0.AE, BV.w, acc[0][3]); \
        acc[1][0] = fmaf(a1.AE, BV.x, acc[1][0]); \
        acc[1][1] = fmaf(a1.AE, BV.y, acc[1][1]); \
        acc[1][2] = fmaf(a1.AE, BV.z, acc[1][2]); \
        acc[1][3] = fmaf(a1.AE, BV.w, acc[1][3]); \
        acc[2][0] = fmaf(a2.AE, BV.x, acc[2][0]); \
        acc[2][1] = fmaf(a2.AE, BV.y, acc[2][1]); \
        acc[2][2] = fmaf(a2.AE, BV.z, acc[2][2]); \
        acc[2][3] = fmaf(a2.AE, BV.w, acc[2][3]); \
        acc[3][0] = fmaf(a3.AE, BV.x, acc[3][0]); \
        acc[3][1] = fmaf(a3.AE, BV.y, acc[3][1]); \
        acc[3][2] = fmaf(a3.AE, BV.z, acc[3][2]); \
        acc[3][3] = fmaf(a3.AE, BV.w, acc[3][3]);
        KK2(x, b0) KK2(y, b1) KK2(z, b2) KK2(w, b3)
#undef KK2
    }
#pragma unroll
    for (int i = 0; i < 4; ++i) {
        int row = row0 + ty4 + i;
        if (row < NN) {
            float s = inv[row];
            union { f16 h[4]; uint2 u; } p;
            p.h[0] = (f16)(acc[i][0] * s);
            p.h[1] = (f16)(acc[i][1] * s);
            p.h[2] = (f16)(acc[i][2] * s);
            p.h[3] = (f16)(acc[i][3] * s);
            *(uint2*)&h2s[(size_t)row * FH + tx4] = p.u;
        } else if (row == NN) {
            *(uint2*)&h2s[(size_t)row * FH + tx4] = make_uint2(0u, 0u);  // guard row
        }
    }
}

// ---------------- agg2: block-per-range LDS accumulate + b2 -> out ---------
__global__ __launch_bounds__(256) void k_agg2(const int2* __restrict__ bucket,
                                              const int* __restrict__ rangeBase,
                                              const float* __restrict__ inv,
                                              const f16* __restrict__ h2s,
                                              const float* __restrict__ b2,
                                              float* __restrict__ out) {
    __shared__ float acc[RSZ * FH];            // 51.2 KB
    int t = threadIdx.x, r = blockIdx.x;
    int n0 = r * RSZ;
    int e0 = __builtin_amdgcn_readfirstlane(rangeBase[r]);
    int e1 = __builtin_amdgcn_readfirstlane(rangeBase[r + 1]);
    for (int idx = t; idx < RSZ * FH; idx += 256)
        acc[idx] = (float)h2s[(size_t)n0 * FH + idx];   // self terms
    __syncthreads();
    int lane = t & 63;
    int wid = t >> 6;
    int p = lane >> 4;
    size_t q8 = (size_t)(lane & 15) * 8;
    int c4 = (lane & 15) * 4;
    const char* hb = (const char*)h2s;
    for (int i = e0 + wid * 4; i < e1; i += 16) {
        int2 ed0 = bucket[i + 0];
        int2 ed1 = bucket[i + 1];
        int2 ed2 = bucket[i + 2];
        int2 ed3 = bucket[i + 3];
        int s_p = sel4(p, ed0.x, ed1.x, ed2.x, ed3.x);
        int d_p = sel4(p, ed0.y, ed1.y, ed2.y, ed3.y);
        if (i + p >= e1) { s_p = NN; d_p = n0; }
        uint2 u = *(const uint2*)(hb + ((size_t)s_p << 7) + q8);
        float f0, f1, f2, f3;
        unpack2(u.x, f0, f1);
        unpack2(u.y, f2, f3);
        int base = (d_p - n0) * FH + c4;
        atomicAdd(&acc[base + 0], f0);
        atomicAdd(&acc[base + 1], f1);
        atomicAdd(&acc[base + 2], f2);
        atomicAdd(&acc[base + 3], f3);
    }
    __syncthreads();
    // epilogue: out[d,0..39] = acc * inv + b2 (contiguous stores)
    for (int idx = t; idx < RSZ * FO; idx += 256) {
        int dloc = idx / FO, f = idx - dloc * FO;
        int d = n0 + dloc;
        out[(size_t)n0 * FO + idx] = acc[dloc * FH + f] * inv[d] + b2[f];
    }
}

extern "C" void kernel_launch(void* const* d_in, const int* in_sizes, int n_in,
                              void* d_out, int out_size, void* d_ws, size_t ws_size,
                              hipStream_t stream) {
    const float* x  = (const float*)d_in[0];
    const int*   ei = (const int*)d_in[1];   // int32 [2, NE]: src = ei[e], dst = ei[NE+e]
    const float* W1 = (const float*)d_in[2];
    const float* b1 = (const float*)d_in[3];
    const float* W2 = (const float*)d_in[4];
    const float* b2 = (const float*)d_in[5];
    float* out = (float*)d_out;

    char* ws = (char*)d_ws;
    int*   blkhist   = (int*)ws;                                  // 1.0 MB
    int*   rtot      = (int*)(ws + (size_t)(1 << 20) + 102400);   // 2 KB
    int*   rangeBase = (int*)(ws + (size_t)(1 << 20) + 106496);   // 2 KB (501)
    float* inv       = (float*)(ws + (size_t)( 2 << 20));         // 0.4 MB
    int2*  bucket    = (int2*)(ws + (size_t)( 4 << 20));          // 12.8 MB (+slack)
    f16*   h0s       = (f16*)(ws + (size_t)(18 << 20));           // 12.8 MB (+row NN)
    f16*   h1s       = (f16*)(ws + (size_t)(31 << 20));           // 12.8 MB
    f16*   h2s       = (f16*)(ws + (size_t)(44 << 20));           // 12.8 MB (+row NN)

    k_p1<<<NBK, 256, 0, stream>>>(ei, blkhist);
    k_scanR1<<<NR, 512, 0, stream>>>(blkhist, rtot);
    k_scanR2<<<1, 512, 0, stream>>>(rtot, rangeBase);
    k_p2<<<NBK, 256, 0, stream>>>(ei, blkhist, rangeBase, bucket);
    k_cnt<<<NR, 256, 0, stream>>>(bucket, rangeBase, inv);

    int gblk = (NN + 63) / 64;   // 1563 (covers zero row NN)
    k_gemm1<<<gblk, 256, 0, stream>>>(x, W1, inv, h0s);
    k_agg1<<<NR, 256, 0, stream>>>(bucket, rangeBase, inv, h0s, b1, h1s);

    k_gemm2<<<gblk, 256, 0, stream>>>(h1s, W2, inv, h2s);
    k_agg2<<<NR, 256, 0, stream>>>(bucket, rangeBase, inv, h2s, b2, out);
}

// Round 18
// 181.686 us; speedup vs baseline: 6.5084x; 6.5084x over previous
//
#include <hip/hip_runtime.h>

#define NN 100000
#define NE 1600000
#define FI 128
#define FH 64
#define FO 40
#define NR 500      // dst ranges
#define RSZ 200     // nodes per range (NR*RSZ == NN)
#define NBK 512     // histogram/scatter blocks

typedef _Float16 f16;
typedef _Float16 f16x2 __attribute__((ext_vector_type(2)));

// ---------------- Threefry-2x32, key = (0, 42) -----------------------------
__device__ __forceinline__ unsigned rotl32(unsigned v, unsigned r) {
    return (v << r) | (v >> (32u - r));
}

__device__ __forceinline__ void threefry_0_42(unsigned x0, unsigned x1,
                                              unsigned& o0, unsigned& o1) {
    const unsigned k0 = 0u, k1 = 42u;
    const unsigned k2 = 0x1BD11BDAu ^ k0 ^ k1;
    x0 += k0; x1 += k1;
#define TFR(r) { x0 += x1; x1 = rotl32(x1, r); x1 ^= x0; }
    TFR(13) TFR(15) TFR(26) TFR(6)   x0 += k1; x1 += k2 + 1u;
    TFR(17) TFR(29) TFR(16) TFR(24)  x0 += k2; x1 += k0 + 2u;
    TFR(13) TFR(15) TFR(26) TFR(6)   x0 += k0; x1 += k1 + 3u;
    TFR(17) TFR(29) TFR(16) TFR(24)  x0 += k1; x1 += k2 + 4u;
    TFR(13) TFR(15) TFR(26) TFR(6)   x0 += k2; x1 += k0 + 5u;
#undef TFR
    o0 = x0; o1 = x1;
}

__device__ __forceinline__ void unpack2(unsigned u, float& lo, float& hi) {
    union { unsigned u; f16 h[2]; } c;
    c.u = u;
    lo = (float)c.h[0];
    hi = (float)c.h[1];
}

// select one of 4 wave-uniform values by per-lane parity p (0..3)
__device__ __forceinline__ int sel4(int p, int s0, int s1, int s2, int s3) {
    int t0 = (p & 1) ? s1 : s0;
    int t1 = (p & 1) ? s3 : s2;
    return (p & 2) ? t1 : t0;
}

// ---------------- P1: per-block LDS range histogram (2 edges/thread) -------
__global__ __launch_bounds__(256) void k_p1(const int* __restrict__ ei,
                                            int* __restrict__ blkhist) {
    __shared__ int h[NR];
    int t = threadIdx.x, b = blockIdx.x;
    for (int i = t; i < NR; i += 256) h[i] = 0;
    __syncthreads();
    for (int base = b * 512 + t * 2; base < NE; base += NBK * 512) {
        int2 dd = *(const int2*)&ei[NE + base];
        atomicAdd(&h[dd.x / RSZ], 1);            // LDS atomic
        atomicAdd(&h[dd.y / RSZ], 1);
    }
    __syncthreads();
    for (int i = t; i < NR; i += 256) blkhist[(size_t)b * NR + i] = h[i];
}

// ---------------- scanR1: per-range exclusive scan over blocks -------------
__global__ __launch_bounds__(512) void k_scanR1(int* __restrict__ blkhist,
                                                int* __restrict__ rtot) {
    __shared__ int sh[NBK];
    int r = blockIdx.x, t = threadIdx.x;
    int v = blkhist[(size_t)t * NR + r];
    sh[t] = v;
    __syncthreads();
    for (int off = 1; off < NBK; off <<= 1) {
        int u = (t >= off) ? sh[t - off] : 0;
        __syncthreads();
        sh[t] += u;
        __syncthreads();
    }
    blkhist[(size_t)t * NR + r] = sh[t] - v;     // block-local prefix
    if (t == NBK - 1) rtot[r] = sh[t];
}

// ---------------- scanR2: exclusive scan of range totals -------------------
__global__ __launch_bounds__(512) void k_scanR2(const int* __restrict__ rtot,
                                                int* __restrict__ rangeBase) {
    __shared__ int sh[512];
    int t = threadIdx.x;
    int v = (t < NR) ? rtot[t] : 0;
    sh[t] = v;
    __syncthreads();
    for (int off = 1; off < 512; off <<= 1) {
        int u = (t >= off) ? sh[t - off] : 0;
        __syncthreads();
        sh[t] += u;
        __syncthreads();
    }
    if (t < NR) rangeBase[t] = sh[t] - v;
    if (t == NR - 1) rangeBase[NR] = sh[t];      // == NE
}

// ---------------- P2: scatter edges, packed 4B (dloc<<17 | src) ------------
__global__ __launch_bounds__(256) void k_p2(const int* __restrict__ ei,
                                            const int* __restrict__ blkhist,
                                            const int* __restrict__ rangeBase,
                                            int* __restrict__ bucket) {
    __shared__ int cur[NR];
    int t = threadIdx.x, b = blockIdx.x;
    for (int i = t; i < NR; i += 256)
        cur[i] = rangeBase[i] + blkhist[(size_t)b * NR + i];
    __syncthreads();
    for (int base = b * 512 + t * 2; base < NE; base += NBK * 512) {  // same slice as k_p1
        int2 ss = *(const int2*)&ei[base];
        int2 dd = *(const int2*)&ei[NE + base];
        int rg0 = dd.x / RSZ;
        int rg1 = dd.y / RSZ;
        int pos0 = atomicAdd(&cur[rg0], 1);               // LDS atomic
        bucket[pos0] = ((dd.x - rg0 * RSZ) << 17) | ss.x;
        int pos1 = atomicAdd(&cur[rg1], 1);
        bucket[pos1] = ((dd.y - rg1 * RSZ) << 17) | ss.y;
    }
}

// ---------------- P3: per-range CSR finalize, segments padded to x4 --------
// Padded entries point to src = NN (all-zero feature row) -> tail-free agg.
__global__ __launch_bounds__(256) void k_p3(const int* __restrict__ bucket,
                                            const int* __restrict__ rangeBase,
                                            int2* __restrict__ odpk,
                                            float* __restrict__ inv,
                                            int* __restrict__ csr_s) {
    __shared__ int cnt[RSZ];
    __shared__ int base[RSZ];
    __shared__ int sc[256];
    int r = blockIdx.x, t = threadIdx.x;
    int e0 = rangeBase[r], e1 = rangeBase[r + 1];
    int padBase = e0 + 3 * RSZ * r;                       // padded global base
    int n0 = r * RSZ;
    if (t < RSZ) cnt[t] = 0;
    __syncthreads();
    for (int i = e0 + t; i < e1; i += 256)
        atomicAdd(&cnt[((unsigned)bucket[i]) >> 17], 1);  // LDS atomic
    __syncthreads();
    int v = 0, vp = 0;
    if (t < RSZ) {
        v = cnt[t];
        vp = (v + 3) & ~3;                                // padded count
    }
    sc[t] = vp;
    __syncthreads();
    for (int off = 1; off < 256; off <<= 1) {
        int u = (t >= off) ? sc[t - off] : 0;
        __syncthreads();
        sc[t] += u;
        __syncthreads();
    }
    int o = 0;
    if (t < RSZ) {
        o = padBase + sc[t] - vp;                         // padded CSR offset
        odpk[n0 + t] = make_int2(o, vp);                  // loop bound = padded
        inv[n0 + t] = rsqrtf((float)v + 1.0f);            // norm from real deg
        base[t] = o;                                      // cursor start
    }
    __syncthreads();
    for (int i = e0 + t; i < e1; i += 256) {
        int pk = bucket[i];
        int dloc = ((unsigned)pk) >> 17;
        int p = atomicAdd(&base[dloc], 1);                // LDS atomic
        csr_s[p] = pk & 0x1FFFF;
    }
    __syncthreads();
    if (t < RSZ) {
        for (int j = v; j < vp; ++j) csr_s[o + j] = NN;   // sentinel pads
    }
}

// ---------------- GEMM1: h0s[N,64] = (x @ W1) * inv[row] (fp16, +zero row) -
#define XS_STRIDE 132   // 128 + 4: keeps b128 16B-aligned; rows on distinct banks
__global__ __launch_bounds__(256) void k_gemm1(const float* __restrict__ x,
                                               const float* __restrict__ W1,
                                               const float* __restrict__ inv,
                                               f16* __restrict__ h0s) {
    __shared__ float xs[64 * XS_STRIDE];   // 33.8 KB
    __shared__ float ws[64 * FH];          // 16 KB (one K-half of W1)
    int t = threadIdx.x;
    int row0 = blockIdx.x * 64;
    {
        int r = t >> 5;              // 0..7
        int c4 = (t & 31) * 4;       // 0..124
#pragma unroll
        for (int p = 0; p < 8; ++p) {
            int row = row0 + r + p * 8;
            float4 v = make_float4(0.f, 0.f, 0.f, 0.f);
            if (row < NN) v = *(const float4*)&x[(size_t)row * FI + c4];
            *(float4*)&xs[(r + p * 8) * XS_STRIDE + c4] = v;
        }
    }
    float acc[4][4] = {{0.f}};
    int tx4 = (t & 15) * 4;
    int ty4 = (t >> 4) * 4;
#pragma unroll
    for (int half = 0; half < 2; ++half) {
        __syncthreads();
        {
            const float4* Wv = (const float4*)(W1 + half * 64 * FH);
            float4* wv = (float4*)ws;
            for (int i = t; i < 64 * FH / 4; i += 256) wv[i] = Wv[i];
        }
        __syncthreads();
#pragma unroll 2
        for (int k = 0; k < 64; k += 4) {
            float4 a0 = *(const float4*)&xs[(ty4 + 0) * XS_STRIDE + half * 64 + k];
            float4 a1 = *(const float4*)&xs[(ty4 + 1) * XS_STRIDE + half * 64 + k];
            float4 a2 = *(const float4*)&xs[(ty4 + 2) * XS_STRIDE + half * 64 + k];
            float4 a3 = *(const float4*)&xs[(ty4 + 3) * XS_STRIDE + half * 64 + k];
            float4 b0 = *(const float4*)&ws[(k + 0) * FH + tx4];
            float4 b1 = *(const float4*)&ws[(k + 1) * FH + tx4];
            float4 b2 = *(const float4*)&ws[(k + 2) * FH + tx4];
            float4 b3 = *(const float4*)&ws[(k + 3) * FH + tx4];
#define KK1(AE, BV) \
            acc[0][0] = fmaf(a0.AE, BV.x, acc[0][0]); \
            acc[0][1] = fmaf(a0.AE, BV.y, acc[0][1]); \
            acc[0][2] = fmaf(a0.AE, BV.z, acc[0][2]); \
            acc[0][3] = fmaf(a0.AE, BV.w, acc[0][3]); \
            acc[1][0] = fmaf(a1.AE, BV.x, acc[1][0]); \
            acc[1][1] = fmaf(a1.AE, BV.y, acc[1][1]); \
            acc[1][2] = fmaf(a1.AE, BV.z, acc[1][2]); \
            acc[1][3] = fmaf(a1.AE, BV.w, acc[1][3]); \
            acc[2][0] = fmaf(a2.AE, BV.x, acc[2][0]); \
            acc[2][1] = fmaf(a2.AE, BV.y, acc[2][1]); \
            acc[2][2] = fmaf(a2.AE, BV.z, acc[2][2]); \
            acc[2][3] = fmaf(a2.AE, BV.w, acc[2][3]); \
            acc[3][0] = fmaf(a3.AE, BV.x, acc[3][0]); \
            acc[3][1] = fmaf(a3.AE, BV.y, acc[3][1]); \
            acc[3][2] = fmaf(a3.AE, BV.z, acc[3][2]); \
            acc[3][3] = fmaf(a3.AE, BV.w, acc[3][3]);
            KK1(x, b0) KK1(y, b1) KK1(z, b2) KK1(w, b3)
#undef KK1
        }
    }
#pragma unroll
    for (int i = 0; i < 4; ++i) {
        int row = row0 + ty4 + i;
        if (row < NN) {
            float s = inv[row];
            union { f16 h[4]; uint2 u; } p;
            p.h[0] = (f16)(acc[i][0] * s);
            p.h[1] = (f16)(acc[i][1] * s);
            p.h[2] = (f16)(acc[i][2] * s);
            p.h[3] = (f16)(acc[i][3] * s);
            *(uint2*)&h0s[(size_t)row * FH + tx4] = p.u;
        } else if (row == NN) {
            *(uint2*)&h0s[(size_t)row * FH + tx4] = make_uint2(0u, 0u);
        }
    }
}

// ---------------- agg1: quad-parity gather (pk_add_f16) + epilogue ---------
__global__ __launch_bounds__(256) void k_agg1(const int2* __restrict__ odpk,
                                              const int* __restrict__ csr_s,
                                              const float* __restrict__ inv,
                                              const f16* __restrict__ h0s,
                                              const float* __restrict__ b1,
                                              f16* __restrict__ h1s) {
    int lane = threadIdx.x & 63;
    int d = __builtin_amdgcn_readfirstlane((int)(blockIdx.x * 4 + (threadIdx.x >> 6)));
    if (d >= NN) return;
    int p = lane >> 4;
    int c4 = (lane & 15) * 4;
    size_t q8 = (size_t)(lane & 15) * 8;       // byte offset within row
    const char* hb = (const char*)h0s;
    int2 od = odpk[d];
    int start = od.x, degp = od.y;             // degp % 4 == 0 (padded)
    float a0 = 0.f, a1 = 0.f, a2 = 0.f, a3 = 0.f;
    int k = 0;
    for (; k + 8 <= degp; k += 8) {
        int s0 = csr_s[start + k + 0], s1 = csr_s[start + k + 1];
        int s2 = csr_s[start + k + 2], s3 = csr_s[start + k + 3];
        int s4 = csr_s[start + k + 4], s5 = csr_s[start + k + 5];
        int s6 = csr_s[start + k + 6], s7 = csr_s[start + k + 7];
        int ia = sel4(p, s0, s1, s2, s3);
        int ib = sel4(p, s4, s5, s6, s7);
        union { uint2 u; f16x2 h[2]; } A, B;
        A.u = *(const uint2*)(hb + ((size_t)ia << 7) + q8);
        B.u = *(const uint2*)(hb + ((size_t)ib << 7) + q8);
        f16x2 p0 = A.h[0] + B.h[0];            // v_pk_add_f16
        f16x2 p1 = A.h[1] + B.h[1];
        a0 += (float)p0[0]; a1 += (float)p0[1];
        a2 += (float)p1[0]; a3 += (float)p1[1];
    }
    if (k < degp) {                            // exactly 4 remain
        int s0 = csr_s[start + k + 0], s1 = csr_s[start + k + 1];
        int s2 = csr_s[start + k + 2], s3 = csr_s[start + k + 3];
        int ia = sel4(p, s0, s1, s2, s3);
        uint2 ua = *(const uint2*)(hb + ((size_t)ia << 7) + q8);
        float f0, f1, f2, f3;
        unpack2(ua.x, f0, f1); unpack2(ua.y, f2, f3);
        a0 += f0; a1 += f1; a2 += f2; a3 += f3;
    }
    // combine 4 parities
    a0 += __shfl_xor(a0, 16, 64); a0 += __shfl_xor(a0, 32, 64);
    a1 += __shfl_xor(a1, 16, 64); a1 += __shfl_xor(a1, 32, 64);
    a2 += __shfl_xor(a2, 16, 64); a2 += __shfl_xor(a2, 32, 64);
    a3 += __shfl_xor(a3, 16, 64); a3 += __shfl_xor(a3, 32, 64);
    // self + bias + relu
    float invd = inv[d];
    uint2 su = *(const uint2*)(hb + ((size_t)d << 7) + q8);
    float s0, s1, s2, s3;
    unpack2(su.x, s0, s1); unpack2(su.y, s2, s3);
    float4 bv = *(const float4*)&b1[c4];
    float v0 = fmaxf((a0 + s0) * invd + bv.x, 0.f);
    float v1 = fmaxf((a1 + s1) * invd + bv.y, 0.f);
    float v2 = fmaxf((a2 + s2) * invd + bv.z, 0.f);
    float v3 = fmaxf((a3 + s3) * invd + bv.w, 0.f);
    // dropout: 1 threefry/lane (feature=lane), pack via ballot, extract 4 bits
    unsigned o0, o1;
    threefry_0_42(0u, (unsigned)(d * FH + lane), o0, o1);
    unsigned long long m = __ballot((int)(((o0 ^ o1) >> 31) ^ 1u));
    unsigned mm = (unsigned)(m >> c4) & 15u;   // keep bits for c4..c4+3
    if (lane < 16) {
        union { f16 h[4]; uint2 u; } st;
        st.h[0] = (f16)((mm & 1u) ? v0 * 2.f : 0.f);
        st.h[1] = (f16)((mm & 2u) ? v1 * 2.f : 0.f);
        st.h[2] = (f16)((mm & 4u) ? v2 * 2.f : 0.f);
        st.h[3] = (f16)((mm & 8u) ? v3 * 2.f : 0.f);
        *(uint2*)&h1s[(size_t)d * FH + c4] = st.u;
    }
}

// ---------------- GEMM2: h2s[N,64pad] = (h1s @ W2) * inv[row] (f16 in/out) -
#define HS_STRIDE 68    // 64 + 4: b128-aligned, rows on distinct banks
__global__ __launch_bounds__(256) void k_gemm2(const f16* __restrict__ h1s,
                                               const float* __restrict__ W2,
                                               const float* __restrict__ inv,
                                               f16* __restrict__ h2s) {
    __shared__ float hs[64 * HS_STRIDE];   // 17.4 KB
    __shared__ float ws[FH * 64];          // 16 KB, cols 40..63 zero
    int t = threadIdx.x;
    int row0 = blockIdx.x * 64;
    {
        int r = t >> 4;              // 0..15
        int c4 = (t & 15) * 4;       // 0..60
#pragma unroll
        for (int p = 0; p < 4; ++p) {
            int row = row0 + r + p * 16;
            float4 v = make_float4(0.f, 0.f, 0.f, 0.f);
            if (row < NN) {
                uint2 u = *(const uint2*)&h1s[(size_t)row * FH + c4];
                unpack2(u.x, v.x, v.y);
                unpack2(u.y, v.z, v.w);
            }
            *(float4*)&hs[(r + p * 16) * HS_STRIDE + c4] = v;
        }
    }
    for (int i = t; i < FH * 64; i += 256) {
        int r = i >> 6, c = i & 63;
        ws[i] = (c < FO) ? W2[r * FO + c] : 0.f;
    }
    __syncthreads();
    float acc[4][4] = {{0.f}};
    int tx4 = (t & 15) * 4;
    int ty4 = (t >> 4) * 4;
#pragma unroll 2
    for (int k = 0; k < FH; k += 4) {
        float4 a0 = *(const float4*)&hs[(ty4 + 0) * HS_STRIDE + k];
        float4 a1 = *(const float4*)&hs[(ty4 + 1) * HS_STRIDE + k];
        float4 a2 = *(const float4*)&hs[(ty4 + 2) * HS_STRIDE + k];
        float4 a3 = *(const float4*)&hs[(ty4 + 3) * HS_STRIDE + k];
        float4 b0 = *(const float4*)&ws[(k + 0) * 64 + tx4];
        float4 b1 = *(const float4*)&ws[(k + 1) * 64 + tx4];
        float4 b2 = *(const float4*)&ws[(k + 2) * 64 + tx4];
        float4 b3 = *(const float4*)&ws[(k + 3) * 64 + tx4];
#define KK2(AE, BV) \
        acc[0][0] = fmaf(a0.AE, BV.x, acc[0][0]); \
        acc[0][1] = fmaf(a0.AE, BV.y, acc[0][1]); \
        acc[0][2] = fmaf(a0.AE, BV.z, acc[0][2]); \
        acc[0][3] = fmaf(a0.AE, BV.w, acc[0][3]); \
        acc[1][0] = fmaf(a1.AE, BV.x, acc[1][0]); \
        acc[1][1] = fmaf(a1.AE, BV.y, acc[1][1]); \
        acc[1][2] = fmaf(a1.AE, BV.z, acc[1][2]); \
        acc[1][3] = fmaf(a1.AE, BV.w, acc[1][3]); \
        acc[2][0] = fmaf(a2.AE, BV.x, acc[2][0]); \
        acc[2][1] = fmaf(a2.AE, BV.y, acc[2][1]); \
        acc[2][2] = fmaf(a2.AE, BV.z, acc[2][2]); \
        acc[2][3] = fmaf(a2.AE, BV.w, acc[2][3]); \
        acc[3][0] = fmaf(a3.AE, BV.x, acc[3][0]); \
        acc[3][1] = fmaf(a3.AE, BV.y, acc[3][1]); \
        acc[3][2] = fmaf(a3.AE, BV.z, acc[3][2]); \
        acc[3][3] = fmaf(a3.AE, BV.w, acc[3][3]);
        KK2(x, b0) KK2(y, b1) KK2(z, b2) KK2(w, b3)
#undef KK2
    }
#pragma unroll
    for (int i = 0; i < 4; ++i) {
        int row = row0 + ty4 + i;
        if (row < NN) {
            float s = inv[row];
            union { f16 h[4]; uint2 u; } p;
            p.h[0] = (f16)(acc[i][0] * s);
            p.h[1] = (f16)(acc[i][1] * s);
            p.h[2] = (f16)(acc[i][2] * s);
            p.h[3] = (f16)(acc[i][3] * s);
            *(uint2*)&h2s[(size_t)row * FH + tx4] = p.u;
        } else if (row == NN) {
            *(uint2*)&h2s[(size_t)row * FH + tx4] = make_uint2(0u, 0u);
        }
    }
}

// ---------------- agg2: quad-parity gather (pk_add_f16) + self + b2 --------
__global__ __launch_bounds__(256) void k_agg2(const int2* __restrict__ odpk,
                                              const int* __restrict__ csr_s,
                                              const float* __restrict__ inv,
                                              const f16* __restrict__ h2s,
                                              const float* __restrict__ b2,
                                              float* __restrict__ out) {
    int lane = threadIdx.x & 63;
    int d = __builtin_amdgcn_readfirstlane((int)(blockIdx.x * 4 + (threadIdx.x >> 6)));
    if (d >= NN) return;
    int p = lane >> 4;
    int c4 = (lane & 15) * 4;
    size_t q8 = (size_t)(lane & 15) * 8;
    const char* hb = (const char*)h2s;
    int2 od = odpk[d];
    int start = od.x, degp = od.y;
    float a0 = 0.f, a1 = 0.f, a2 = 0.f, a3 = 0.f;
    int k = 0;
    for (; k + 8 <= degp; k += 8) {
        int s0 = csr_s[start + k + 0], s1 = csr_s[start + k + 1];
        int s2 = csr_s[start + k + 2], s3 = csr_s[start + k + 3];
        int s4 = csr_s[start + k + 4], s5 = csr_s[start + k + 5];
        int s6 = csr_s[start + k + 6], s7 = csr_s[start + k + 7];
        int ia = sel4(p, s0, s1, s2, s3);
        int ib = sel4(p, s4, s5, s6, s7);
        union { uint2 u; f16x2 h[2]; } A, B;
        A.u = *(const uint2*)(hb + ((size_t)ia << 7) + q8);
        B.u = *(const uint2*)(hb + ((size_t)ib << 7) + q8);
        f16x2 p0 = A.h[0] + B.h[0];            // v_pk_add_f16
        f16x2 p1 = A.h[1] + B.h[1];
        a0 += (float)p0[0]; a1 += (float)p0[1];
        a2 += (float)p1[0]; a3 += (float)p1[1];
    }
    if (k < degp) {
        int s0 = csr_s[start + k + 0], s1 = csr_s[start + k + 1];
        int s2 = csr_s[start + k + 2], s3 = csr_s[start + k + 3];
        int ia = sel4(p, s0, s1, s2, s3);
        uint2 ua = *(const uint2*)(hb + ((size_t)ia << 7) + q8);
        float f0, f1, f2, f3;
        unpack2(ua.x, f0, f1); unpack2(ua.y, f2, f3);
        a0 += f0; a1 += f1; a2 += f2; a3 += f3;
    }
    a0 += __shfl_xor(a0, 16, 64); a0 += __shfl_xor(a0, 32, 64);
    a1 += __shfl_xor(a1, 16, 64); a1 += __shfl_xor(a1, 32, 64);
    a2 += __shfl_xor(a2, 16, 64); a2 += __shfl_xor(a2, 32, 64);
    a3 += __shfl_xor(a3, 16, 64); a3 += __shfl_xor(a3, 32, 64);
    if (lane < 10) {                           // c4 <= 36 -> cols 0..39
        float invd = inv[d];
        uint2 su = *(const uint2*)(hb + ((size_t)d << 7) + q8);
        float s0, s1, s2, s3;
        unpack2(su.x, s0, s1); unpack2(su.y, s2, s3);
        float4 bv = *(const float4*)&b2[c4];
        float4 st;
        st.x = (a0 + s0) * invd + bv.x;
        st.y = (a1 + s1) * invd + bv.y;
        st.z = (a2 + s2) * invd + bv.z;
        st.w = (a3 + s3) * invd + bv.w;
        *(float4*)&out[(size_t)d * FO + c4] = st;
    }
}

extern "C" void kernel_launch(void* const* d_in, const int* in_sizes, int n_in,
                              void* d_out, int out_size, void* d_ws, size_t ws_size,
                              hipStream_t stream) {
    const float* x  = (const float*)d_in[0];
    const int*   ei = (const int*)d_in[1];   // int32 [2, NE]: src = ei[e], dst = ei[NE+e]
    const float* W1 = (const float*)d_in[2];
    const float* b1 = (const float*)d_in[3];
    const float* W2 = (const float*)d_in[4];
    const float* b2 = (const float*)d_in[5];
    float* out = (float*)d_out;

    char* ws = (char*)d_ws;
    int*   blkhist   = (int*)ws;                                  // 1.0 MB
    int*   rtot      = (int*)(ws + (size_t)(1 << 20) + 102400);   // 2 KB
    int*   rangeBase = (int*)(ws + (size_t)(1 << 20) + 106496);   // 2 KB (501)
    float* inv       = (float*)(ws + (size_t)( 2 << 20));         // 0.4 MB
    int2*  odpk      = (int2*)(ws + (size_t)( 3 << 20));          // 0.8 MB
    int*   bucket    = (int*)(ws + (size_t)( 4 << 20));           // 6.4 MB (packed; dead after p3)
    f16*   h2s       = (f16*)(ws + (size_t)( 4 << 20));           // 12.8 MB (reuses bucket region)
    int*   csr_s     = (int*)(ws + (size_t)(17 << 20));           // <=7.6 MB (padded)
    f16*   h0s       = (f16*)(ws + (size_t)(25 << 20));           // 12.8 MB (+row NN)
    f16*   h1s       = (f16*)(ws + (size_t)(38 << 20));           // 12.8 MB

    k_p1<<<NBK, 256, 0, stream>>>(ei, blkhist);
    k_scanR1<<<NR, 512, 0, stream>>>(blkhist, rtot);
    k_scanR2<<<1, 512, 0, stream>>>(rtot, rangeBase);
    k_p2<<<NBK, 256, 0, stream>>>(ei, blkhist, rangeBase, bucket);
    k_p3<<<NR, 256, 0, stream>>>(bucket, rangeBase, odpk, inv, csr_s);

    int gblk = (NN + 63) / 64;   // 1563 (covers zero row NN at row0=99968..100031)
    k_gemm1<<<gblk, 256, 0, stream>>>(x, W1, inv, h0s);
    k_agg1<<<NN / 4, 256, 0, stream>>>(odpk, csr_s, inv, h0s, b1, h1s);

    k_gemm2<<<gblk, 256, 0, stream>>>(h1s, W2, inv, h2s);
    k_agg2<<<NN / 4, 256, 0, stream>>>(odpk, csr_s, inv, h2s, b2, out);
}

// Round 19
// 177.812 us; speedup vs baseline: 6.6502x; 1.0218x over previous
//
#include <hip/hip_runtime.h>

#define NN 100000
#define NE 1600000
#define FI 128
#define FH 64
#define FO 40
#define NR 500      // dst ranges
#define RSZ 200     // nodes per range (NR*RSZ == NN)
#define NBK 512     // histogram/scatter blocks

typedef _Float16 f16;
typedef _Float16 f16x2 __attribute__((ext_vector_type(2)));

// ---------------- Threefry-2x32, key = (0, 42) -----------------------------
__device__ __forceinline__ unsigned rotl32(unsigned v, unsigned r) {
    return (v << r) | (v >> (32u - r));
}

__device__ __forceinline__ void threefry_0_42(unsigned x0, unsigned x1,
                                              unsigned& o0, unsigned& o1) {
    const unsigned k0 = 0u, k1 = 42u;
    const unsigned k2 = 0x1BD11BDAu ^ k0 ^ k1;
    x0 += k0; x1 += k1;
#define TFR(r) { x0 += x1; x1 = rotl32(x1, r); x1 ^= x0; }
    TFR(13) TFR(15) TFR(26) TFR(6)   x0 += k1; x1 += k2 + 1u;
    TFR(17) TFR(29) TFR(16) TFR(24)  x0 += k2; x1 += k0 + 2u;
    TFR(13) TFR(15) TFR(26) TFR(6)   x0 += k0; x1 += k1 + 3u;
    TFR(17) TFR(29) TFR(16) TFR(24)  x0 += k1; x1 += k2 + 4u;
    TFR(13) TFR(15) TFR(26) TFR(6)   x0 += k2; x1 += k0 + 5u;
#undef TFR
    o0 = x0; o1 = x1;
}

__device__ __forceinline__ void unpack2(unsigned u, float& lo, float& hi) {
    union { unsigned u; f16 h[2]; } c;
    c.u = u;
    lo = (float)c.h[0];
    hi = (float)c.h[1];
}

// select one of 4 wave-uniform values by per-lane parity p (0..3)
__device__ __forceinline__ int sel4(int p, int s0, int s1, int s2, int s3) {
    int t0 = (p & 1) ? s1 : s0;
    int t1 = (p & 1) ? s3 : s2;
    return (p & 2) ? t1 : t0;
}

// ---------------- P1: per-block LDS range histogram (2 edges/thread) -------
__global__ __launch_bounds__(256) void k_p1(const int* __restrict__ ei,
                                            int* __restrict__ blkhist) {
    __shared__ int h[NR];
    int t = threadIdx.x, b = blockIdx.x;
    for (int i = t; i < NR; i += 256) h[i] = 0;
    __syncthreads();
    for (int base = b * 512 + t * 2; base < NE; base += NBK * 512) {
        int2 dd = *(const int2*)&ei[NE + base];
        atomicAdd(&h[dd.x / RSZ], 1);            // LDS atomic
        atomicAdd(&h[dd.y / RSZ], 1);
    }
    __syncthreads();
    for (int i = t; i < NR; i += 256) blkhist[(size_t)b * NR + i] = h[i];
}

// ---------------- scanR1: per-range exclusive scan over blocks -------------
__global__ __launch_bounds__(512) void k_scanR1(int* __restrict__ blkhist,
                                                int* __restrict__ rtot) {
    __shared__ int sh[NBK];
    int r = blockIdx.x, t = threadIdx.x;
    int v = blkhist[(size_t)t * NR + r];
    sh[t] = v;
    __syncthreads();
    for (int off = 1; off < NBK; off <<= 1) {
        int u = (t >= off) ? sh[t - off] : 0;
        __syncthreads();
        sh[t] += u;
        __syncthreads();
    }
    blkhist[(size_t)t * NR + r] = sh[t] - v;     // block-local prefix
    if (t == NBK - 1) rtot[r] = sh[t];
}

// ---------------- scanR2: exclusive scan of range totals -------------------
__global__ __launch_bounds__(512) void k_scanR2(const int* __restrict__ rtot,
                                                int* __restrict__ rangeBase) {
    __shared__ int sh[512];
    int t = threadIdx.x;
    int v = (t < NR) ? rtot[t] : 0;
    sh[t] = v;
    __syncthreads();
    for (int off = 1; off < 512; off <<= 1) {
        int u = (t >= off) ? sh[t - off] : 0;
        __syncthreads();
        sh[t] += u;
        __syncthreads();
    }
    if (t < NR) rangeBase[t] = sh[t] - v;
    if (t == NR - 1) rangeBase[NR] = sh[t];      // == NE
}

// ---------------- P2: scatter edges, packed 4B (dloc<<17 | src) ------------
__global__ __launch_bounds__(256) void k_p2(const int* __restrict__ ei,
                                            const int* __restrict__ blkhist,
                                            const int* __restrict__ rangeBase,
                                            int* __restrict__ bucket) {
    __shared__ int cur[NR];
    int t = threadIdx.x, b = blockIdx.x;
    for (int i = t; i < NR; i += 256)
        cur[i] = rangeBase[i] + blkhist[(size_t)b * NR + i];
    __syncthreads();
    for (int base = b * 512 + t * 2; base < NE; base += NBK * 512) {  // same slice as k_p1
        int2 ss = *(const int2*)&ei[base];
        int2 dd = *(const int2*)&ei[NE + base];
        int rg0 = dd.x / RSZ;
        int rg1 = dd.y / RSZ;
        int pos0 = atomicAdd(&cur[rg0], 1);               // LDS atomic
        bucket[pos0] = ((dd.x - rg0 * RSZ) << 17) | ss.x;
        int pos1 = atomicAdd(&cur[rg1], 1);
        bucket[pos1] = ((dd.y - rg1 * RSZ) << 17) | ss.y;
    }
}

// ---------------- P3: per-range CSR finalize, segments padded to x4 --------
// Padded entries point to src = NN (all-zero feature row) -> tail-free agg.
__global__ __launch_bounds__(256) void k_p3(const int* __restrict__ bucket,
                                            const int* __restrict__ rangeBase,
                                            int2* __restrict__ odpk,
                                            float* __restrict__ inv,
                                            int* __restrict__ csr_s) {
    __shared__ int cnt[RSZ];
    __shared__ int base[RSZ];
    __shared__ int sc[256];
    int r = blockIdx.x, t = threadIdx.x;
    int e0 = rangeBase[r], e1 = rangeBase[r + 1];
    int padBase = e0 + 3 * RSZ * r;                       // padded global base
    int n0 = r * RSZ;
    if (t < RSZ) cnt[t] = 0;
    __syncthreads();
    for (int i = e0 + t; i < e1; i += 256)
        atomicAdd(&cnt[((unsigned)bucket[i]) >> 17], 1);  // LDS atomic
    __syncthreads();
    int v = 0, vp = 0;
    if (t < RSZ) {
        v = cnt[t];
        vp = (v + 3) & ~3;                                // padded count
    }
    sc[t] = vp;
    __syncthreads();
    for (int off = 1; off < 256; off <<= 1) {
        int u = (t >= off) ? sc[t - off] : 0;
        __syncthreads();
        sc[t] += u;
        __syncthreads();
    }
    int o = 0;
    if (t < RSZ) {
        o = padBase + sc[t] - vp;                         // padded CSR offset
        odpk[n0 + t] = make_int2(o, vp);                  // loop bound = padded
        inv[n0 + t] = rsqrtf((float)v + 1.0f);            // norm from real deg
        base[t] = o;                                      // cursor start
    }
    __syncthreads();
    for (int i = e0 + t; i < e1; i += 256) {
        int pk = bucket[i];
        int dloc = ((unsigned)pk) >> 17;
        int p = atomicAdd(&base[dloc], 1);                // LDS atomic
        csr_s[p] = pk & 0x1FFFF;
    }
    __syncthreads();
    if (t < RSZ) {
        for (int j = v; j < vp; ++j) csr_s[o + j] = NN;   // sentinel pads
    }
}

// ---------------- GEMM1: h0s[N,64] = (x @ W1) * inv[row] (fp16, +zero row) -
// x staged in two 64-col halves -> LDS 33.4 KB -> 4 blocks/CU (2x occupancy).
#define XS_STRIDE 68    // 64 + 4: b128-aligned, rows on distinct banks
__global__ __launch_bounds__(256) void k_gemm1(const float* __restrict__ x,
                                               const float* __restrict__ W1,
                                               const float* __restrict__ inv,
                                               f16* __restrict__ h0s) {
    __shared__ float xs[64 * XS_STRIDE];   // 17.4 KB (one K-half of x tile)
    __shared__ float ws[64 * FH];          // 16 KB (one K-half of W1)
    int t = threadIdx.x;
    int row0 = blockIdx.x * 64;
    float acc[4][4] = {{0.f}};
    int tx4 = (t & 15) * 4;
    int ty4 = (t >> 4) * 4;
    int sr = t >> 4;              // 0..15
    int sc4 = (t & 15) * 4;       // 0..60
#pragma unroll
    for (int half = 0; half < 2; ++half) {
        __syncthreads();
        // stage x half: 64 rows x cols [half*64, half*64+64)
#pragma unroll
        for (int p = 0; p < 4; ++p) {
            int row = row0 + sr + p * 16;
            float4 v = make_float4(0.f, 0.f, 0.f, 0.f);
            if (row < NN) v = *(const float4*)&x[(size_t)row * FI + half * 64 + sc4];
            *(float4*)&xs[(sr + p * 16) * XS_STRIDE + sc4] = v;
        }
        // stage W half
        {
            const float4* Wv = (const float4*)(W1 + half * 64 * FH);
            float4* wv = (float4*)ws;
            for (int i = t; i < 64 * FH / 4; i += 256) wv[i] = Wv[i];
        }
        __syncthreads();
#pragma unroll 2
        for (int k = 0; k < 64; k += 4) {
            float4 a0 = *(const float4*)&xs[(ty4 + 0) * XS_STRIDE + k];
            float4 a1 = *(const float4*)&xs[(ty4 + 1) * XS_STRIDE + k];
            float4 a2 = *(const float4*)&xs[(ty4 + 2) * XS_STRIDE + k];
            float4 a3 = *(const float4*)&xs[(ty4 + 3) * XS_STRIDE + k];
            float4 b0 = *(const float4*)&ws[(k + 0) * FH + tx4];
            float4 b1 = *(const float4*)&ws[(k + 1) * FH + tx4];
            float4 b2 = *(const float4*)&ws[(k + 2) * FH + tx4];
            float4 b3 = *(const float4*)&ws[(k + 3) * FH + tx4];
#define KK1(AE, BV) \
            acc[0][0] = fmaf(a0.AE, BV.x, acc[0][0]); \
            acc[0][1] = fmaf(a0.AE, BV.y, acc[0][1]); \
            acc[0][2] = fmaf(a0.AE, BV.z, acc[0][2]); \
            acc[0][3] = fmaf(a0.AE, BV.w, acc[0][3]); \
            acc[1][0] = fmaf(a1.AE, BV.x, acc[1][0]); \
            acc[1][1] = fmaf(a1.AE, BV.y, acc[1][1]); \
            acc[1][2] = fmaf(a1.AE, BV.z, acc[1][2]); \
            acc[1][3] = fmaf(a1.AE, BV.w, acc[1][3]); \
            acc[2][0] = fmaf(a2.AE, BV.x, acc[2][0]); \
            acc[2][1] = fmaf(a2.AE, BV.y, acc[2][1]); \
            acc[2][2] = fmaf(a2.AE, BV.z, acc[2][2]); \
            acc[2][3] = fmaf(a2.AE, BV.w, acc[2][3]); \
            acc[3][0] = fmaf(a3.AE, BV.x, acc[3][0]); \
            acc[3][1] = fmaf(a3.AE, BV.y, acc[3][1]); \
            acc[3][2] = fmaf(a3.AE, BV.z, acc[3][2]); \
            acc[3][3] = fmaf(a3.AE, BV.w, acc[3][3]);
            KK1(x, b0) KK1(y, b1) KK1(z, b2) KK1(w, b3)
#undef KK1
        }
    }
#pragma unroll
    for (int i = 0; i < 4; ++i) {
        int row = row0 + ty4 + i;
        if (row < NN) {
            float s = inv[row];
            union { f16 h[4]; uint2 u; } p;
            p.h[0] = (f16)(acc[i][0] * s);
            p.h[1] = (f16)(acc[i][1] * s);
            p.h[2] = (f16)(acc[i][2] * s);
            p.h[3] = (f16)(acc[i][3] * s);
            *(uint2*)&h0s[(size_t)row * FH + tx4] = p.u;
        } else if (row == NN) {
            *(uint2*)&h0s[(size_t)row * FH + tx4] = make_uint2(0u, 0u);
        }
    }
}

// ---------------- agg1: quad-parity gather (pk_add_f16) + epilogue ---------
__global__ __launch_bounds__(256) void k_agg1(const int2* __restrict__ odpk,
                                              const int* __restrict__ csr_s,
                                              const float* __restrict__ inv,
                                              const f16* __restrict__ h0s,
                                              const float* __restrict__ b1,
                                              f16* __restrict__ h1s) {
    int lane = threadIdx.x & 63;
    int d = __builtin_amdgcn_readfirstlane((int)(blockIdx.x * 4 + (threadIdx.x >> 6)));
    if (d >= NN) return;
    int p = lane >> 4;
    int c4 = (lane & 15) * 4;
    size_t q8 = (size_t)(lane & 15) * 8;       // byte offset within row
    const char* hb = (const char*)h0s;
    int2 od = odpk[d];
    int start = od.x, degp = od.y;             // degp % 4 == 0 (padded)
    float a0 = 0.f, a1 = 0.f, a2 = 0.f, a3 = 0.f;
    int k = 0;
    for (; k + 8 <= degp; k += 8) {
        int s0 = csr_s[start + k + 0], s1 = csr_s[start + k + 1];
        int s2 = csr_s[start + k + 2], s3 = csr_s[start + k + 3];
        int s4 = csr_s[start + k + 4], s5 = csr_s[start + k + 5];
        int s6 = csr_s[start + k + 6], s7 = csr_s[start + k + 7];
        int ia = sel4(p, s0, s1, s2, s3);
        int ib = sel4(p, s4, s5, s6, s7);
        union { uint2 u; f16x2 h[2]; } A, B;
        A.u = *(const uint2*)(hb + ((size_t)ia << 7) + q8);
        B.u = *(const uint2*)(hb + ((size_t)ib << 7) + q8);
        f16x2 p0 = A.h[0] + B.h[0];            // v_pk_add_f16
        f16x2 p1 = A.h[1] + B.h[1];
        a0 += (float)p0[0]; a1 += (float)p0[1];
        a2 += (float)p1[0]; a3 += (float)p1[1];
    }
    if (k < degp) {                            // exactly 4 remain
        int s0 = csr_s[start + k + 0], s1 = csr_s[start + k + 1];
        int s2 = csr_s[start + k + 2], s3 = csr_s[start + k + 3];
        int ia = sel4(p, s0, s1, s2, s3);
        uint2 ua = *(const uint2*)(hb + ((size_t)ia << 7) + q8);
        float f0, f1, f2, f3;
        unpack2(ua.x, f0, f1); unpack2(ua.y, f2, f3);
        a0 += f0; a1 += f1; a2 += f2; a3 += f3;
    }
    // combine 4 parities
    a0 += __shfl_xor(a0, 16, 64); a0 += __shfl_xor(a0, 32, 64);
    a1 += __shfl_xor(a1, 16, 64); a1 += __shfl_xor(a1, 32, 64);
    a2 += __shfl_xor(a2, 16, 64); a2 += __shfl_xor(a2, 32, 64);
    a3 += __shfl_xor(a3, 16, 64); a3 += __shfl_xor(a3, 32, 64);
    // self + bias + relu
    float invd = inv[d];
    uint2 su = *(const uint2*)(hb + ((size_t)d << 7) + q8);
    float s0, s1, s2, s3;
    unpack2(su.x, s0, s1); unpack2(su.y, s2, s3);
    float4 bv = *(const float4*)&b1[c4];
    float v0 = fmaxf((a0 + s0) * invd + bv.x, 0.f);
    float v1 = fmaxf((a1 + s1) * invd + bv.y, 0.f);
    float v2 = fmaxf((a2 + s2) * invd + bv.z, 0.f);
    float v3 = fmaxf((a3 + s3) * invd + bv.w, 0.f);
    // dropout: 1 threefry/lane (feature=lane), pack via ballot, extract 4 bits
    unsigned o0, o1;
    threefry_0_42(0u, (unsigned)(d * FH + lane), o0, o1);
    unsigned long long m = __ballot((int)(((o0 ^ o1) >> 31) ^ 1u));
    unsigned mm = (unsigned)(m >> c4) & 15u;   // keep bits for c4..c4+3
    if (lane < 16) {
        union { f16 h[4]; uint2 u; } st;
        st.h[0] = (f16)((mm & 1u) ? v0 * 2.f : 0.f);
        st.h[1] = (f16)((mm & 2u) ? v1 * 2.f : 0.f);
        st.h[2] = (f16)((mm & 4u) ? v2 * 2.f : 0.f);
        st.h[3] = (f16)((mm & 8u) ? v3 * 2.f : 0.f);
        *(uint2*)&h1s[(size_t)d * FH + c4] = st.u;
    }
}

// ---------------- GEMM2: h2s[N,64pad] = (h1s @ W2) * inv[row] (f16 in/out) -
#define HS_STRIDE 68    // 64 + 4: b128-aligned, rows on distinct banks
__global__ __launch_bounds__(256) void k_gemm2(const f16* __restrict__ h1s,
                                               const float* __restrict__ W2,
                                               const float* __restrict__ inv,
                                               f16* __restrict__ h2s) {
    __shared__ float hs[64 * HS_STRIDE];   // 17.4 KB
    __shared__ float ws[FH * 64];          // 16 KB, cols 40..63 zero
    int t = threadIdx.x;
    int row0 = blockIdx.x * 64;
    {
        int r = t >> 4;              // 0..15
        int c4 = (t & 15) * 4;       // 0..60
#pragma unroll
        for (int p = 0; p < 4; ++p) {
            int row = row0 + r + p * 16;
            float4 v = make_float4(0.f, 0.f, 0.f, 0.f);
            if (row < NN) {
                uint2 u = *(const uint2*)&h1s[(size_t)row * FH + c4];
                unpack2(u.x, v.x, v.y);
                unpack2(u.y, v.z, v.w);
            }
            *(float4*)&hs[(r + p * 16) * HS_STRIDE + c4] = v;
        }
    }
    for (int i = t; i < FH * 64; i += 256) {
        int r = i >> 6, c = i & 63;
        ws[i] = (c < FO) ? W2[r * FO + c] : 0.f;
    }
    __syncthreads();
    float acc[4][4] = {{0.f}};
    int tx4 = (t & 15) * 4;
    int ty4 = (t >> 4) * 4;
#pragma unroll 2
    for (int k = 0; k < FH; k += 4) {
        float4 a0 = *(const float4*)&hs[(ty4 + 0) * HS_STRIDE + k];
        float4 a1 = *(const float4*)&hs[(ty4 + 1) * HS_STRIDE + k];
        float4 a2 = *(const float4*)&hs[(ty4 + 2) * HS_STRIDE + k];
        float4 a3 = *(const float4*)&hs[(ty4 + 3) * HS_STRIDE + k];
        float4 b0 = *(const float4*)&ws[(k + 0) * 64 + tx4];
        float4 b1 = *(const float4*)&ws[(k + 1) * 64 + tx4];
        float4 b2 = *(const float4*)&ws[(k + 2) * 64 + tx4];
        float4 b3 = *(const float4*)&ws[(k + 3) * 64 + tx4];
#define KK2(AE, BV) \
        acc[0][0] = fmaf(a0.AE, BV.x, acc[0][0]); \
        acc[0][1] = fmaf(a0.AE, BV.y, acc[0][1]); \
        acc[0][2] = fmaf(a0.AE, BV.z, acc[0][2]); \
        acc[0][3] = fmaf(a0.AE, BV.w, acc[0][3]); \
        acc[1][0] = fmaf(a1.AE, BV.x, acc[1][0]); \
        acc[1][1] = fmaf(a1.AE, BV.y, acc[1][1]); \
        acc[1][2] = fmaf(a1.AE, BV.z, acc[1][2]); \
        acc[1][3] = fmaf(a1.AE, BV.w, acc[1][3]); \
        acc[2][0] = fmaf(a2.AE, BV.x, acc[2][0]); \
        acc[2][1] = fmaf(a2.AE, BV.y, acc[2][1]); \
        acc[2][2] = fmaf(a2.AE, BV.z, acc[2][2]); \
        acc[2][3] = fmaf(a2.AE, BV.w, acc[2][3]); \
        acc[3][0] = fmaf(a3.AE, BV.x, acc[3][0]); \
        acc[3][1] = fmaf(a3.AE, BV.y, acc[3][1]); \
        acc[3][2] = fmaf(a3.AE, BV.z, acc[3][2]); \
        acc[3][3] = fmaf(a3.AE, BV.w, acc[3][3]);
        KK2(x, b0) KK2(y, b1) KK2(z, b2) KK2(w, b3)
#undef KK2
    }
#pragma unroll
    for (int i = 0; i < 4; ++i) {
        int row = row0 + ty4 + i;
        if (row < NN) {
            float s = inv[row];
            union { f16 h[4]; uint2 u; } p;
            p.h[0] = (f16)(acc[i][0] * s);
            p.h[1] = (f16)(acc[i][1] * s);
            p.h[2] = (f16)(acc[i][2] * s);
            p.h[3] = (f16)(acc[i][3] * s);
            *(uint2*)&h2s[(size_t)row * FH + tx4] = p.u;
        } else if (row == NN) {
            *(uint2*)&h2s[(size_t)row * FH + tx4] = make_uint2(0u, 0u);
        }
    }
}

// ---------------- agg2: quad-parity gather (pk_add_f16) + self + b2 --------
__global__ __launch_bounds__(256) void k_agg2(const int2* __restrict__ odpk,
                                              const int* __restrict__ csr_s,
                                              const float* __restrict__ inv,
                                              const f16* __restrict__ h2s,
                                              const float* __restrict__ b2,
                                              float* __restrict__ out) {
    int lane = threadIdx.x & 63;
    int d = __builtin_amdgcn_readfirstlane((int)(blockIdx.x * 4 + (threadIdx.x >> 6)));
    if (d >= NN) return;
    int p = lane >> 4;
    int c4 = (lane & 15) * 4;
    size_t q8 = (size_t)(lane & 15) * 8;
    const char* hb = (const char*)h2s;
    int2 od = odpk[d];
    int start = od.x, degp = od.y;
    float a0 = 0.f, a1 = 0.f, a2 = 0.f, a3 = 0.f;
    int k = 0;
    for (; k + 8 <= degp; k += 8) {
        int s0 = csr_s[start + k + 0], s1 = csr_s[start + k + 1];
        int s2 = csr_s[start + k + 2], s3 = csr_s[start + k + 3];
        int s4 = csr_s[start + k + 4], s5 = csr_s[start + k + 5];
        int s6 = csr_s[start + k + 6], s7 = csr_s[start + k + 7];
        int ia = sel4(p, s0, s1, s2, s3);
        int ib = sel4(p, s4, s5, s6, s7);
        union { uint2 u; f16x2 h[2]; } A, B;
        A.u = *(const uint2*)(hb + ((size_t)ia << 7) + q8);
        B.u = *(const uint2*)(hb + ((size_t)ib << 7) + q8);
        f16x2 p0 = A.h[0] + B.h[0];            // v_pk_add_f16
        f16x2 p1 = A.h[1] + B.h[1];
        a0 += (float)p0[0]; a1 += (float)p0[1];
        a2 += (float)p1[0]; a3 += (float)p1[1];
    }
    if (k < degp) {
        int s0 = csr_s[start + k + 0], s1 = csr_s[start + k + 1];
        int s2 = csr_s[start + k + 2], s3 = csr_s[start + k + 3];
        int ia = sel4(p, s0, s1, s2, s3);
        uint2 ua = *(const uint2*)(hb + ((size_t)ia << 7) + q8);
        float f0, f1, f2, f3;
        unpack2(ua.x, f0, f1); unpack2(ua.y, f2, f3);
        a0 += f0; a1 += f1; a2 += f2; a3 += f3;
    }
    a0 += __shfl_xor(a0, 16, 64); a0 += __shfl_xor(a0, 32, 64);
    a1 += __shfl_xor(a1, 16, 64); a1 += __shfl_xor(a1, 32, 64);
    a2 += __shfl_xor(a2, 16, 64); a2 += __shfl_xor(a2, 32, 64);
    a3 += __shfl_xor(a3, 16, 64); a3 += __shfl_xor(a3, 32, 64);
    if (lane < 10) {                           // c4 <= 36 -> cols 0..39
        float invd = inv[d];
        uint2 su = *(const uint2*)(hb + ((size_t)d << 7) + q8);
        float s0, s1, s2, s3;
        unpack2(su.x, s0, s1); unpack2(su.y, s2, s3);
        float4 bv = *(const float4*)&b2[c4];
        float4 st;
        st.x = (a0 + s0) * invd + bv.x;
        st.y = (a1 + s1) * invd + bv.y;
        st.z = (a2 + s2) * invd + bv.z;
        st.w = (a3 + s3) * invd + bv.w;
        *(float4*)&out[(size_t)d * FO + c4] = st;
    }
}

extern "C" void kernel_launch(void* const* d_in, const int* in_sizes, int n_in,
                              void* d_out, int out_size, void* d_ws, size_t ws_size,
                              hipStream_t stream) {
    const float* x  = (const float*)d_in[0];
    const int*   ei = (const int*)d_in[1];   // int32 [2, NE]: src = ei[e], dst = ei[NE+e]
    const float* W1 = (const float*)d_in[2];
    const float* b1 = (const float*)d_in[3];
    const float* W2 = (const float*)d_in[4];
    const float* b2 = (const float*)d_in[5];
    float* out = (float*)d_out;

    char* ws = (char*)d_ws;
    int*   blkhist   = (int*)ws;                                  // 1.0 MB
    int*   rtot      = (int*)(ws + (size_t)(1 << 20) + 102400);   // 2 KB
    int*   rangeBase = (int*)(ws + (size_t)(1 << 20) + 106496);   // 2 KB (501)
    float* inv       = (float*)(ws + (size_t)( 2 << 20));         // 0.4 MB
    int2*  odpk      = (int2*)(ws + (size_t)( 3 << 20));          // 0.8 MB
    int*   bucket    = (int*)(ws + (size_t)( 4 << 20));           // 6.4 MB (packed; dead after p3)
    f16*   h2s       = (f16*)(ws + (size_t)( 4 << 20));           // 12.8 MB (reuses bucket region)
    int*   csr_s     = (int*)(ws + (size_t)(17 << 20));           // <=7.6 MB (padded)
    f16*   h0s       = (f16*)(ws + (size_t)(25 << 20));           // 12.8 MB (+row NN)
    f16*   h1s       = (f16*)(ws + (size_t)(38 << 20));           // 12.8 MB

    k_p1<<<NBK, 256, 0, stream>>>(ei, blkhist);
    k_scanR1<<<NR, 512, 0, stream>>>(blkhist, rtot);
    k_scanR2<<<1, 512, 0, stream>>>(rtot, rangeBase);
    k_p2<<<NBK, 256, 0, stream>>>(ei, blkhist, rangeBase, bucket);
    k_p3<<<NR, 256, 0, stream>>>(bucket, rangeBase, odpk, inv, csr_s);

    int gblk = (NN + 63) / 64;   // 1563 (covers zero row NN at row0=99968..100031)
    k_gemm1<<<gblk, 256, 0, stream>>>(x, W1, inv, h0s);
    k_agg1<<<NN / 4, 256, 0, stream>>>(odpk, csr_s, inv, h0s, b1, h1s);

    k_gemm2<<<gblk, 256, 0, stream>>>(h1s, W2, inv, h2s);
    k_agg2<<<NN / 4, 256, 0, stream>>>(odpk, csr_s, inv, h2s, b2, out);
}